// Round 12
// baseline (130.060 us; speedup 1.0000x reference)
//
#include <hip/hip_runtime.h>

// Problem constants (from reference)
#define NN 4096
#define CC 128
#define II 9
#define DD 9
#define EE 10
#define PP3 23
#define PP2 5
#define PP1 3
// symmetric monomial counts over 9 vars
#define F3 165   // i<=j<=k
#define F2 45    // i<=j
#define F1 9
#define FTOT (F3 + F2 + F1)  // 219
#define FPAD 224             // padded K (7 x 32)
#define NKT 7                // K-tiles of 32

// workspace layout (bytes)
#define SU3_ELEMS (F3 * PP3 * DD)              // 34155 floats
#define SU2_ELEMS (F2 * PP2 * DD)              // 2025 floats
#define SU3_OFF 0
#define SU2_OFF (SU3_OFF + SU3_ELEMS * 4)
#define CUR_OFF (SU2_OFF + SU2_ELEMS * 4)
#define LIST_OFF (CUR_OFF + 64)                // 16 ints + pad
#define WG16_OFF (LIST_OFF + NN * EE * 4)      // f16 W images: E*C*16*224*2 = 9.2 MB

#define SPLIT3 2
#define TSTRIDE (SPLIT3 * 4)   // tile stride per wave: SPLIT3 blocks x 4 waves

typedef _Float16 f16x8 __attribute__((ext_vector_type(8)));
typedef __fp16 fp16x2 __attribute__((ext_vector_type(2)));   // cvt_pkrtz return type
typedef float f32x4 __attribute__((ext_vector_type(4)));

static __device__ __forceinline__ unsigned pkrtz(float a, float b) {
    fp16x2 h = __builtin_amdgcn_cvt_pkrtz(a, b);
    return __builtin_bit_cast(unsigned, h);
}

static __device__ __forceinline__ unsigned short h16(float a) {
    _Float16 ha = (_Float16)a;
    return __builtin_bit_cast(unsigned short, ha);
}

__global__ void zero_cursors_kernel(int* cursors) {
    if (threadIdx.x < 16) cursors[threadIdx.x] = 0;
}

// Atomic append bucketing. List ORDER is nondeterministic, but each node's
// result is a fixed-order dot product independent of its list slot, so
// d_out is bit-deterministic.
__global__ void bucket_kernel(const int* __restrict__ indices,
                              int* __restrict__ cursors,
                              int* __restrict__ lists) {
    int b = blockIdx.x * blockDim.x + threadIdx.x;
    if (b < NN) {
        int e = indices[b];
        int slot = atomicAdd(&cursors[e], 1);
        lists[e * NN + slot] = b;
    }
}

// Symmetrize u3 over (i,j,k) and u2 over (i,j) into monomial-indexed tensors.
__global__ void sym_u_kernel(const float* __restrict__ u3,
                             const float* __restrict__ u2,
                             float* __restrict__ su3,
                             float* __restrict__ su2) {
    int gid = blockIdx.x * blockDim.x + threadIdx.x;
    if (gid < F3 * PP3) {
        int t = gid / PP3, p = gid % PP3;
        int I0 = 0, J0 = 0, K0 = 0;
        {
            int rem = t;
            bool found = false;
            for (int i = 0; i < 9 && !found; i++)
                for (int j = i; j < 9 && !found; j++) {
                    int cnt = 9 - j;
                    if (rem < cnt) { I0 = i; J0 = j; K0 = j + rem; found = true; }
                    else rem -= cnt;
                }
        }
        int a[3] = {I0, J0, K0};
        const int ord[6][3] = {{0,1,2},{0,2,1},{1,0,2},{1,2,0},{2,0,1},{2,1,0}};
        int codes[6], pi[6], pj[6], pk[6];
        int np = 0;
        for (int q = 0; q < 6; q++) {
            int ii = a[ord[q][0]], jj = a[ord[q][1]], kk = a[ord[q][2]];
            int code = (ii * 9 + jj) * 9 + kk;
            bool seen = false;
            for (int r = 0; r < np; r++) if (codes[r] == code) seen = true;
            if (!seen) { codes[np] = code; pi[np] = ii; pj[np] = jj; pk[np] = kk; np++; }
        }
        for (int d = 0; d < 9; d++) {
            float s = 0.f;
            for (int q = 0; q < np; q++)
                s += u3[((((d * 9 + pi[q]) * 9 + pj[q]) * 9 + pk[q]) * PP3) + p];
            su3[(t * PP3 + p) * 9 + d] = s;
        }
    } else if (gid < F3 * PP3 + F2 * PP2) {
        int r = gid - F3 * PP3;
        int t = r / PP2, p = r % PP2;
        int I0 = 0, J0 = 0;
        {
            int rem = t;
            bool found = false;
            for (int i = 0; i < 9 && !found; i++) {
                int cnt = 9 - i;
                if (rem < cnt) { I0 = i; J0 = i + rem; found = true; }
                else rem -= cnt;
            }
        }
        for (int d = 0; d < 9; d++) {
            float s = u2[(((d * 9 + I0) * 9 + J0) * PP2) + p];
            if (I0 != J0) s += u2[(((d * 9 + J0) * 9 + I0) * PP2) + p];
            su2[(t * PP2 + p) * 9 + d] = s;
        }
    }
}

// Precompute per-(e,c) f16 weight image, layout [d (16, col)][f (224, K)].
// One thread per f: su3 rows read as float4 vector loads, w-weights
// block-uniform (SGPR), output staged in LDS, copied out coalesced.
__global__ __launch_bounds__(256) void wprep16_kernel(
    const float* __restrict__ su3,
    const float* __restrict__ su2,
    const float* __restrict__ u1,
    const float* __restrict__ w3,
    const float* __restrict__ w2,
    const float* __restrict__ w1,
    unsigned* __restrict__ Wg16)
{
    const int c = blockIdx.x;
    const int e = blockIdx.y;
    const int tid = threadIdx.x;

    __shared__ unsigned short sImg[16 * FPAD];   // 7 KB f16 image [d][f]
    unsigned* sImgW = reinterpret_cast<unsigned*>(sImg);
    for (int q = tid; q < 16 * FPAD / 2; q += 256) sImgW[q] = 0u;
    __syncthreads();

    if (tid < FTOT) {
        float acc[9];
        #pragma unroll
        for (int d = 0; d < 9; d++) acc[d] = 0.f;

        if (tid < F3) {
            const float* sp = su3 + (size_t)tid * PP3 * 9;
            #pragma unroll
            for (int p = 0; p < PP3; p++) {
                const float wv = w3[(e * PP3 + p) * CC + c];     // uniform -> SGPR
                const float4 a = *reinterpret_cast<const float4*>(sp + p * 9);
                const float4 b = *reinterpret_cast<const float4*>(sp + p * 9 + 4);
                const float g = sp[p * 9 + 8];
                acc[0] += wv * a.x; acc[1] += wv * a.y; acc[2] += wv * a.z; acc[3] += wv * a.w;
                acc[4] += wv * b.x; acc[5] += wv * b.y; acc[6] += wv * b.z; acc[7] += wv * b.w;
                acc[8] += wv * g;
            }
        } else if (tid < F3 + F2) {
            const float* sp = su2 + (size_t)(tid - F3) * PP2 * 9;
            #pragma unroll
            for (int p = 0; p < PP2; p++) {
                const float wv = w2[(e * PP2 + p) * CC + c];
                const float4 a = *reinterpret_cast<const float4*>(sp + p * 9);
                const float4 b = *reinterpret_cast<const float4*>(sp + p * 9 + 4);
                const float g = sp[p * 9 + 8];
                acc[0] += wv * a.x; acc[1] += wv * a.y; acc[2] += wv * a.z; acc[3] += wv * a.w;
                acc[4] += wv * b.x; acc[5] += wv * b.y; acc[6] += wv * b.z; acc[7] += wv * b.w;
                acc[8] += wv * g;
            }
        } else {
            const int i = tid - F3 - F2;
            #pragma unroll
            for (int p = 0; p < PP1; p++) {
                const float wv = w1[(e * PP1 + p) * CC + c];
                #pragma unroll
                for (int d = 0; d < 9; d++)
                    acc[d] += wv * u1[(d * 9 + i) * PP1 + p];
            }
        }
        #pragma unroll
        for (int d = 0; d < 9; d++)
            sImg[d * FPAD + tid] = h16(acc[d]);
    }
    __syncthreads();

    unsigned* dst = Wg16 + (size_t)(e * CC + c) * (16 * FPAD / 2);
    for (int q = tid; q < 16 * FPAD / 2; q += 256) dst[q] = sImgW[q];
}

// Main kernel, round 11/12: barrier-free, LDS-free. One wave owns one
// 16-node MFMA tile at a time. Each lane computes the FULL 219-monomial
// stream for node (lane&15) in registers (4x redundant across lane
// groups), packs to f16 pairs with v_cvt_pkrtz, and keeps only its
// bg-chunk of the A fragment via compile-time-indexed selects
// (rule-#20-safe: all array indices fold to constants). No __syncthreads
// anywhere; x-row loads are software-pipelined one tile ahead.
__global__ __launch_bounds__(256, 4) void symcon_reg_kernel(
    const float* __restrict__ x,
    const unsigned short* __restrict__ Wg16,
    const int* __restrict__ cursors,
    const int* __restrict__ lists,
    float* __restrict__ out)
{
    const int c = blockIdx.x;
    const int e = blockIdx.y;
    const int s = blockIdx.z;
    const int lane = threadIdx.x & 63;
    const int wid = threadIdx.x >> 6;
    const int bcol = lane & 15;
    const int bg = lane >> 4;

    // B fragments: lane holds B[k = t*32 + bg*8 + j][col = bcol]
    f16x8 bfrag[NKT];
    {
        const unsigned short* wp = Wg16 + (size_t)(e * CC + c) * (16 * FPAD);
        #pragma unroll
        for (int t = 0; t < NKT; t++)
            bfrag[t] = *reinterpret_cast<const f16x8*>(wp + bcol * FPAD + t * 32 + bg * 8);
    }

    const bool isg1 = (bg == 1), isg2 = (bg == 2), isg3 = (bg == 3);

    const int cnt = cursors[e];
    const int ntiles = (cnt + 15) >> 4;

    int T = s * 4 + wid;
    float xv[9];
    {
        const int n = T * 16 + bcol;
        const bool valid = (T < ntiles) && (n < cnt);
        const int b = valid ? lists[e * NN + n] : 0;
        const float* xr = x + ((size_t)b * CC + c) * II;
        #pragma unroll
        for (int q = 0; q < 9; q++) xv[q] = valid ? xr[q] : 0.f;
    }

    while (T < ntiles) {
        // ---- prefetch next tile's x row (hidden under this tile's work) ----
        const int Tn = T + TSTRIDE;
        float xn[9];
        {
            const int n = Tn * 16 + bcol;
            const bool valid = (Tn < ntiles) && (n < cnt);
            const int b = valid ? lists[e * NN + n] : 0;
            const float* xr = x + ((size_t)b * CC + c) * II;
            #pragma unroll
            for (int q = 0; q < 9; q++) xn[q] = valid ? xr[q] : 0.f;
        }

        // ---- monomial stream -> A fragments (registers only) ----
        unsigned au[NKT][4];
        {
            float pend = 0.f;
            int F = 0;
            // Pair P = F>>1 maps to tile t=P>>4, lane-group g=(P>>2)&3,
            // dword jd=P&3 — all compile-time after unroll. Lane keeps pairs
            // whose g matches its bg; g==0 write is unconditional (init).
#define EMITR(expr) { const float _m = (expr);                                \
            if (F & 1) { const unsigned _pk = pkrtz(pend, _m);                \
                const int _P = F >> 1; const int _t = _P >> 4;                \
                const int _g = (_P >> 2) & 3; const int _jd = _P & 3;         \
                if (_g == 0)      au[_t][_jd] = _pk;                          \
                else if (_g == 1) au[_t][_jd] = isg1 ? _pk : au[_t][_jd];     \
                else if (_g == 2) au[_t][_jd] = isg2 ? _pk : au[_t][_jd];     \
                else              au[_t][_jd] = isg3 ? _pk : au[_t][_jd];     \
            } else pend = _m; F++; }
            #pragma unroll
            for (int i = 0; i < 9; i++)
                #pragma unroll
                for (int j = i; j < 9; j++) {
                    const float xij = xv[i] * xv[j];
                    #pragma unroll
                    for (int k = j; k < 9; k++)
                        EMITR(xij * xv[k])
                }
            #pragma unroll
            for (int i = 0; i < 9; i++)
                #pragma unroll
                for (int j = i; j < 9; j++)
                    EMITR(xv[i] * xv[j])
            #pragma unroll
            for (int i = 0; i < 9; i++)
                EMITR(xv[i])
            #pragma unroll
            for (int z = 0; z < 5; z++)   // zero-pad f 219..223
                EMITR(0.f)
#undef EMITR
        }

        // ---- MFMA: 7 K-tiles ----
        f32x4 acc = {0.f, 0.f, 0.f, 0.f};
        #pragma unroll
        for (int t = 0; t < NKT; t++) {
            f16x8 af;
            unsigned* ap = reinterpret_cast<unsigned*>(&af);
            ap[0] = au[t][0]; ap[1] = au[t][1];
            ap[2] = au[t][2]; ap[3] = au[t][3];
            acc = __builtin_amdgcn_mfma_f32_16x16x32_f16(af, bfrag[t], acc, 0, 0, 0);
        }

        // ---- scatter D: col = bcol (= d), row = bg*4 + p (= node slot) ----
        if (bcol < 9) {
            const int slot = T * 16 + bg * 4;
            const int4 nb4 = *reinterpret_cast<const int4*>(&lists[e * NN + slot]);
            const int ids[4] = {nb4.x, nb4.y, nb4.z, nb4.w};
            #pragma unroll
            for (int p = 0; p < 4; p++) {
                if (slot + p < cnt)
                    out[((size_t)ids[p] * CC + c) * DD + bcol] = acc[p];
            }
        }

        #pragma unroll
        for (int q = 0; q < 9; q++) xv[q] = xn[q];
        T = Tn;
    }
}

extern "C" void kernel_launch(void* const* d_in, const int* in_sizes, int n_in,
                              void* d_out, int out_size, void* d_ws, size_t ws_size,
                              hipStream_t stream) {
    const float* x   = (const float*)d_in[0];
    const int* indices = (const int*)d_in[1];
    const float* u3  = (const float*)d_in[2];
    const float* u2  = (const float*)d_in[3];
    const float* u1  = (const float*)d_in[4];
    const float* w3  = (const float*)d_in[5];
    const float* w2  = (const float*)d_in[6];
    const float* w1  = (const float*)d_in[7];
    float* out = (float*)d_out;

    char* ws = (char*)d_ws;
    float* su3 = (float*)(ws + SU3_OFF);
    float* su2 = (float*)(ws + SU2_OFF);
    int* cursors = (int*)(ws + CUR_OFF);
    int* lists = (int*)(ws + LIST_OFF);
    unsigned* Wg16 = (unsigned*)(ws + WG16_OFF);

    hipLaunchKernelGGL(zero_cursors_kernel, dim3(1), dim3(64), 0, stream, cursors);
    hipLaunchKernelGGL(bucket_kernel, dim3((NN + 255) / 256), dim3(256), 0, stream,
                       indices, cursors, lists);
    hipLaunchKernelGGL(sym_u_kernel, dim3((F3 * PP3 + F2 * PP2 + 255) / 256), dim3(256),
                       0, stream, u3, u2, su3, su2);
    hipLaunchKernelGGL(wprep16_kernel, dim3(CC, EE), dim3(256), 0, stream,
                       su3, su2, u1, w3, w2, w1, Wg16);
    hipLaunchKernelGGL(symcon_reg_kernel, dim3(CC, EE, SPLIT3), dim3(256), 0, stream,
                       x, (const unsigned short*)Wg16, cursors, lists, out);
}

// Round 13
// 117.543 us; speedup vs baseline: 1.1065x; 1.1065x over previous
//
#include <hip/hip_runtime.h>

// Problem constants (from reference)
#define NN 4096
#define CC 128
#define II 9
#define DD 9
#define EE 10
#define PP3 23
#define PP2 5
#define PP1 3
// symmetric monomial counts over 9 vars
#define F3 165   // i<=j<=k
#define F2 45    // i<=j
#define F1 9
#define FTOT (F3 + F2 + F1)  // 219
#define FPAD 224             // padded K (14 x 16)
#define NKT14 14             // K-tiles of 16 (32x32x16 MFMA)

// workspace layout (bytes)
#define SU3_ELEMS (F3 * PP3 * DD)              // 34155 floats
#define SU2_ELEMS (F2 * PP2 * DD)              // 2025 floats
#define SU3_OFF 0
#define SU2_OFF (SU3_OFF + SU3_ELEMS * 4)
#define CUR_OFF (SU2_OFF + SU2_ELEMS * 4)
#define LIST_OFF (CUR_OFF + 64)                // 16 ints + pad
#define WG16_OFF (LIST_OFF + NN * EE * 4)      // f16 W images: E*C*9*224*2 = 5.2 MB

#define CPB 4      // channels per block (1 per wave)
#define TS 4       // tile-stride (grid z)

typedef _Float16 f16x8 __attribute__((ext_vector_type(8)));
typedef __fp16 fp16x2 __attribute__((ext_vector_type(2)));   // cvt_pkrtz return type
typedef float f32x16 __attribute__((ext_vector_type(16)));

static __device__ __forceinline__ unsigned pkrtz(float a, float b) {
    fp16x2 h = __builtin_amdgcn_cvt_pkrtz(a, b);
    return __builtin_bit_cast(unsigned, h);
}

static __device__ __forceinline__ unsigned short h16(float a) {
    _Float16 ha = (_Float16)a;
    return __builtin_bit_cast(unsigned short, ha);
}

// Fused: symmetrize u3/u2 (one thread per (t,p,d) output element — round-13:
// was one thread per (t,p), 9x fewer threads and latency-bound) + zero the
// bucket cursors (16 spare threads).
__global__ void sym_u_zero_kernel(const float* __restrict__ u3,
                                  const float* __restrict__ u2,
                                  float* __restrict__ su3,
                                  float* __restrict__ su2,
                                  int* __restrict__ cursors) {
    int gid = blockIdx.x * blockDim.x + threadIdx.x;
    if (gid < F3 * PP3 * 9) {
        const int t = gid / (PP3 * 9);
        const int rr = gid % (PP3 * 9);
        const int p = rr / 9;
        const int d = rr % 9;
        int I0 = 0, J0 = 0, K0 = 0;
        {
            int rem = t;
            bool found = false;
            for (int i = 0; i < 9 && !found; i++)
                for (int j = i; j < 9 && !found; j++) {
                    int cnt = 9 - j;
                    if (rem < cnt) { I0 = i; J0 = j; K0 = j + rem; found = true; }
                    else rem -= cnt;
                }
        }
        int a[3] = {I0, J0, K0};
        const int ord[6][3] = {{0,1,2},{0,2,1},{1,0,2},{1,2,0},{2,0,1},{2,1,0}};
        int codes[6];
        int np = 0;
        float s = 0.f;
        for (int q = 0; q < 6; q++) {
            int ii = a[ord[q][0]], jj = a[ord[q][1]], kk = a[ord[q][2]];
            int code = (ii * 9 + jj) * 9 + kk;
            bool seen = false;
            for (int r = 0; r < np; r++) if (codes[r] == code) seen = true;
            if (!seen) {
                codes[np++] = code;
                s += u3[(((((d * 9 + ii) * 9 + jj) * 9 + kk)) * PP3) + p];
            }
        }
        su3[(t * PP3 + p) * 9 + d] = s;
    } else if (gid < F3 * PP3 * 9 + F2 * PP2 * 9) {
        const int g2 = gid - F3 * PP3 * 9;
        const int t = g2 / (PP2 * 9);
        const int rr = g2 % (PP2 * 9);
        const int p = rr / 9;
        const int d = rr % 9;
        int I0 = 0, J0 = 0;
        {
            int rem = t;
            bool found = false;
            for (int i = 0; i < 9 && !found; i++) {
                int cnt = 9 - i;
                if (rem < cnt) { I0 = i; J0 = i + rem; found = true; }
                else rem -= cnt;
            }
        }
        float s = u2[(((d * 9 + I0) * 9 + J0) * PP2) + p];
        if (I0 != J0) s += u2[(((d * 9 + J0) * 9 + I0) * PP2) + p];
        su2[(t * PP2 + p) * 9 + d] = s;
    } else if (gid < F3 * PP3 * 9 + F2 * PP2 * 9 + 16) {
        cursors[gid - (F3 * PP3 * 9 + F2 * PP2 * 9)] = 0;
    }
}

// Atomic append bucketing. List ORDER is nondeterministic, but each node's
// result is a fixed-order dot product independent of its list slot, so
// d_out is bit-deterministic.
__global__ void bucket_kernel(const int* __restrict__ indices,
                              int* __restrict__ cursors,
                              int* __restrict__ lists) {
    int b = blockIdx.x * blockDim.x + threadIdx.x;
    if (b < NN) {
        int e = indices[b];
        int slot = atomicAdd(&cursors[e], 1);
        lists[e * NN + slot] = b;
    }
}

// Precompute per-(e,c) f16 weight image, layout [d (9 rows)][f (224, K)].
// One thread per f: su3 rows read as float4 vector loads, w-weights
// block-uniform (SGPR), output staged in LDS, copied out coalesced.
__global__ __launch_bounds__(256) void wprep16_kernel(
    const float* __restrict__ su3,
    const float* __restrict__ su2,
    const float* __restrict__ u1,
    const float* __restrict__ w3,
    const float* __restrict__ w2,
    const float* __restrict__ w1,
    unsigned* __restrict__ Wg16)
{
    const int c = blockIdx.x;
    const int e = blockIdx.y;
    const int tid = threadIdx.x;

    __shared__ unsigned short sImg[9 * FPAD];   // 4 KB f16 image [d][f]
    unsigned* sImgW = reinterpret_cast<unsigned*>(sImg);
    for (int q = tid; q < 9 * FPAD / 2; q += 256) sImgW[q] = 0u;
    __syncthreads();

    if (tid < FTOT) {
        float acc[9];
        #pragma unroll
        for (int d = 0; d < 9; d++) acc[d] = 0.f;

        if (tid < F3) {
            const float* sp = su3 + (size_t)tid * PP3 * 9;
            #pragma unroll
            for (int p = 0; p < PP3; p++) {
                const float wv = w3[(e * PP3 + p) * CC + c];     // uniform -> SGPR
                const float4 a = *reinterpret_cast<const float4*>(sp + p * 9);
                const float4 b = *reinterpret_cast<const float4*>(sp + p * 9 + 4);
                const float g = sp[p * 9 + 8];
                acc[0] += wv * a.x; acc[1] += wv * a.y; acc[2] += wv * a.z; acc[3] += wv * a.w;
                acc[4] += wv * b.x; acc[5] += wv * b.y; acc[6] += wv * b.z; acc[7] += wv * b.w;
                acc[8] += wv * g;
            }
        } else if (tid < F3 + F2) {
            const float* sp = su2 + (size_t)(tid - F3) * PP2 * 9;
            #pragma unroll
            for (int p = 0; p < PP2; p++) {
                const float wv = w2[(e * PP2 + p) * CC + c];
                const float4 a = *reinterpret_cast<const float4*>(sp + p * 9);
                const float4 b = *reinterpret_cast<const float4*>(sp + p * 9 + 4);
                const float g = sp[p * 9 + 8];
                acc[0] += wv * a.x; acc[1] += wv * a.y; acc[2] += wv * a.z; acc[3] += wv * a.w;
                acc[4] += wv * b.x; acc[5] += wv * b.y; acc[6] += wv * b.z; acc[7] += wv * b.w;
                acc[8] += wv * g;
            }
        } else {
            const int i = tid - F3 - F2;
            #pragma unroll
            for (int p = 0; p < PP1; p++) {
                const float wv = w1[(e * PP1 + p) * CC + c];
                #pragma unroll
                for (int d = 0; d < 9; d++)
                    acc[d] += wv * u1[(d * 9 + i) * PP1 + p];
            }
        }
        #pragma unroll
        for (int d = 0; d < 9; d++)
            sImg[d * FPAD + tid] = h16(acc[d]);
    }
    __syncthreads();

    unsigned* dst = Wg16 + (size_t)(e * CC + c) * (9 * FPAD / 2);
    for (int q = tid; q < 9 * FPAD / 2; q += 256) dst[q] = sImgW[q];
}

// Main kernel, round 13: 32x32x16 MFMA, barrier/LDS-free, channel-blocked.
// Grid (32 c-chunks, E, TS). Block = 4 waves, wave w owns channel
// c = bx*4 + w for ALL its tiles (tiles strided by TS). A wave covers a
// 32-node tile: lane (g=lane>>5, r=lane&31) computes the full 224-entry
// monomial stream for node r (2x redundancy), keeps its g-half of each
// K-tile's A fragment (4 dwords), and fires one MFMA per 16-f K-tile
// interleaved into the stream (au[] stays 4 regs; bfrag 14x4=56 regs).
// x reads: 4 consecutive channels per block -> 144B contiguous per node.
__global__ __launch_bounds__(256, 4) void symcon_reg32_kernel(
    const float* __restrict__ x,
    const unsigned short* __restrict__ Wg16,
    const int* __restrict__ cursors,
    const int* __restrict__ lists,
    float* __restrict__ out)
{
    const int e = blockIdx.y;
    const int lane = threadIdx.x & 63;
    const int wid = threadIdx.x >> 6;
    const int c = blockIdx.x * CPB + wid;
    const int r = lane & 31;       // node row within tile; also B col (= d)
    const int g = lane >> 5;       // k-half
    const bool isg1 = (g == 1);

    // B fragments: lane holds B[k = t*16 + g*8 + j][col = r], zeros for col>=9
    f16x8 bfrag[NKT14];
    {
        const unsigned short* wp = Wg16 + (size_t)(e * CC + c) * (9 * FPAD);
        #pragma unroll
        for (int t = 0; t < NKT14; t++) {
            f16x8 v = {0, 0, 0, 0, 0, 0, 0, 0};
            if (r < 9)
                v = *reinterpret_cast<const f16x8*>(wp + r * FPAD + t * 16 + g * 8);
            bfrag[t] = v;
        }
    }

    const int cnt = cursors[e];
    const int ntiles = (cnt + 31) >> 5;

    int T = blockIdx.z;
    float xv[9];
    {
        const int n = T * 32 + r;
        const bool valid = (T < ntiles) && (n < cnt);
        const int b = valid ? lists[e * NN + n] : 0;
        const float* xr = x + ((size_t)b * CC + c) * II;
        #pragma unroll
        for (int q = 0; q < 9; q++) xv[q] = valid ? xr[q] : 0.f;
    }

    while (T < ntiles) {
        // ---- prefetch next tile's x row ----
        const int Tn = T + TS;
        float xn[9];
        {
            const int n = Tn * 32 + r;
            const bool valid = (Tn < ntiles) && (n < cnt);
            const int b = valid ? lists[e * NN + n] : 0;
            const float* xr = x + ((size_t)b * CC + c) * II;
            #pragma unroll
            for (int q = 0; q < 9; q++) xn[q] = valid ? xr[q] : 0.f;
        }

        // ---- monomial stream with interleaved MFMA ----
        f32x16 acc = {0.f, 0.f, 0.f, 0.f, 0.f, 0.f, 0.f, 0.f,
                      0.f, 0.f, 0.f, 0.f, 0.f, 0.f, 0.f, 0.f};
        unsigned au[4];
        {
            float pend = 0.f;
            int F = 0;
            // Pair P = F>>1: K-tile t = P>>3, q = P&7, half gg = q>>2,
            // dword jd = q&3 — all compile-time after unroll. q<4 writes are
            // unconditional (g1 lanes overwritten by their q>=4 select).
            // At q==7 the tile's fragment is complete -> MFMA.
#define EMITR(expr) { const float _m = (expr);                                \
            if (F & 1) { const unsigned _pk = pkrtz(pend, _m);                \
                const int _P = F >> 1; const int _t = _P >> 3;                \
                const int _q = _P & 7; const int _jd = _q & 3;                \
                if (_q < 4) au[_jd] = _pk;                                    \
                else        au[_jd] = isg1 ? _pk : au[_jd];                   \
                if (_q == 7) {                                                \
                    f16x8 af;                                                 \
                    unsigned* _ap = reinterpret_cast<unsigned*>(&af);         \
                    _ap[0] = au[0]; _ap[1] = au[1];                           \
                    _ap[2] = au[2]; _ap[3] = au[3];                           \
                    acc = __builtin_amdgcn_mfma_f32_32x32x16_f16(             \
                        af, bfrag[_t], acc, 0, 0, 0);                         \
                }                                                             \
            } else pend = _m; F++; }
            #pragma unroll
            for (int i = 0; i < 9; i++)
                #pragma unroll
                for (int j = i; j < 9; j++) {
                    const float xij = xv[i] * xv[j];
                    #pragma unroll
                    for (int k = j; k < 9; k++)
                        EMITR(xij * xv[k])
                }
            #pragma unroll
            for (int i = 0; i < 9; i++)
                #pragma unroll
                for (int j = i; j < 9; j++)
                    EMITR(xv[i] * xv[j])
            #pragma unroll
            for (int i = 0; i < 9; i++)
                EMITR(xv[i])
            #pragma unroll
            for (int z = 0; z < 10; z++)   // zero-pad f 219..223 + round to 224
                EMITR(0.f)
#undef EMITR
        }

        // ---- scatter D: col = r (= d), row = (reg&3) + 8*(reg>>2) + 4*g ----
        if (r < 9) {
            #pragma unroll
            for (int reg = 0; reg < 16; reg++) {
                const int row = (reg & 3) + 8 * (reg >> 2) + 4 * g;
                const int slot = T * 32 + row;
                if (slot < cnt) {
                    const int b = lists[e * NN + slot];
                    out[((size_t)b * CC + c) * DD + r] = acc[reg];
                }
            }
        }

        #pragma unroll
        for (int q = 0; q < 9; q++) xv[q] = xn[q];
        T = Tn;
    }
}

extern "C" void kernel_launch(void* const* d_in, const int* in_sizes, int n_in,
                              void* d_out, int out_size, void* d_ws, size_t ws_size,
                              hipStream_t stream) {
    const float* x   = (const float*)d_in[0];
    const int* indices = (const int*)d_in[1];
    const float* u3  = (const float*)d_in[2];
    const float* u2  = (const float*)d_in[3];
    const float* u1  = (const float*)d_in[4];
    const float* w3  = (const float*)d_in[5];
    const float* w2  = (const float*)d_in[6];
    const float* w1  = (const float*)d_in[7];
    float* out = (float*)d_out;

    char* ws = (char*)d_ws;
    float* su3 = (float*)(ws + SU3_OFF);
    float* su2 = (float*)(ws + SU2_OFF);
    int* cursors = (int*)(ws + CUR_OFF);
    int* lists = (int*)(ws + LIST_OFF);
    unsigned* Wg16 = (unsigned*)(ws + WG16_OFF);

    const int symn = F3 * PP3 * 9 + F2 * PP2 * 9 + 16;
    hipLaunchKernelGGL(sym_u_zero_kernel, dim3((symn + 255) / 256), dim3(256), 0, stream,
                       u3, u2, su3, su2, cursors);
    hipLaunchKernelGGL(bucket_kernel, dim3((NN + 255) / 256), dim3(256), 0, stream,
                       indices, cursors, lists);
    hipLaunchKernelGGL(wprep16_kernel, dim3(CC, EE), dim3(256), 0, stream,
                       su3, su2, u1, w3, w2, w1, Wg16);
    hipLaunchKernelGGL(symcon_reg32_kernel, dim3(CC / CPB, EE, TS), dim3(256), 0, stream,
                       x, (const unsigned short*)Wg16, cursors, lists, out);
}

// Round 14
// 99.370 us; speedup vs baseline: 1.3088x; 1.1829x over previous
//
#include <hip/hip_runtime.h>

// Problem constants (from reference)
#define NN 4096
#define CC 128
#define II 9
#define DD 9
#define EE 10
#define PP3 23
#define PP2 5
#define PP1 3
// symmetric monomial counts over 9 vars
#define F3 165   // i<=j<=k
#define F2 45    // i<=j
#define F1 9
#define FTOT (F3 + F2 + F1)  // 219
#define FPAD 224             // padded K (14 x 16)
#define NKT14 14             // K-tiles of 16 (32x32x16 MFMA)

// workspace layout (bytes)
#define SU3_ELEMS (F3 * PP3 * DD)              // 34155 floats
#define SU2_ELEMS (F2 * PP2 * DD)              // 2025 floats
#define SU3_OFF 0
#define SU2_OFF (SU3_OFF + SU3_ELEMS * 4)
#define CUR_OFF (SU2_OFF + SU2_ELEMS * 4)
#define LIST_OFF (CUR_OFF + 64)                // 16 ints + pad
#define WG16_OFF (LIST_OFF + NN * EE * 4)      // f16 W images: E*C*9*224*2 = 5.2 MB

#define CPB 4      // channels per block (1 per wave)
#define TS 8       // tile-stride (grid z) — round-14: 2560 blocks, smoother balance

typedef _Float16 f16x8 __attribute__((ext_vector_type(8)));
typedef __fp16 fp16x2 __attribute__((ext_vector_type(2)));   // cvt_pkrtz return type
typedef float f32x16 __attribute__((ext_vector_type(16)));

static __device__ __forceinline__ unsigned pkrtz(float a, float b) {
    fp16x2 h = __builtin_amdgcn_cvt_pkrtz(a, b);
    return __builtin_bit_cast(unsigned, h);
}

static __device__ __forceinline__ unsigned short h16(float a) {
    _Float16 ha = (_Float16)a;
    return __builtin_bit_cast(unsigned short, ha);
}

// Fused: symmetrize u3/u2 (one thread per (t,p,d) output element) + zero
// the bucket cursors (16 spare threads).
__global__ void sym_u_zero_kernel(const float* __restrict__ u3,
                                  const float* __restrict__ u2,
                                  float* __restrict__ su3,
                                  float* __restrict__ su2,
                                  int* __restrict__ cursors) {
    int gid = blockIdx.x * blockDim.x + threadIdx.x;
    if (gid < F3 * PP3 * 9) {
        const int t = gid / (PP3 * 9);
        const int rr = gid % (PP3 * 9);
        const int p = rr / 9;
        const int d = rr % 9;
        int I0 = 0, J0 = 0, K0 = 0;
        {
            int rem = t;
            bool found = false;
            for (int i = 0; i < 9 && !found; i++)
                for (int j = i; j < 9 && !found; j++) {
                    int cnt = 9 - j;
                    if (rem < cnt) { I0 = i; J0 = j; K0 = j + rem; found = true; }
                    else rem -= cnt;
                }
        }
        int a[3] = {I0, J0, K0};
        const int ord[6][3] = {{0,1,2},{0,2,1},{1,0,2},{1,2,0},{2,0,1},{2,1,0}};
        int codes[6];
        int np = 0;
        float s = 0.f;
        for (int q = 0; q < 6; q++) {
            int ii = a[ord[q][0]], jj = a[ord[q][1]], kk = a[ord[q][2]];
            int code = (ii * 9 + jj) * 9 + kk;
            bool seen = false;
            for (int r = 0; r < np; r++) if (codes[r] == code) seen = true;
            if (!seen) {
                codes[np++] = code;
                s += u3[(((((d * 9 + ii) * 9 + jj) * 9 + kk)) * PP3) + p];
            }
        }
        su3[(t * PP3 + p) * 9 + d] = s;
    } else if (gid < F3 * PP3 * 9 + F2 * PP2 * 9) {
        const int g2 = gid - F3 * PP3 * 9;
        const int t = g2 / (PP2 * 9);
        const int rr = g2 % (PP2 * 9);
        const int p = rr / 9;
        const int d = rr % 9;
        int I0 = 0, J0 = 0;
        {
            int rem = t;
            bool found = false;
            for (int i = 0; i < 9 && !found; i++) {
                int cnt = 9 - i;
                if (rem < cnt) { I0 = i; J0 = i + rem; found = true; }
                else rem -= cnt;
            }
        }
        float s = u2[(((d * 9 + I0) * 9 + J0) * PP2) + p];
        if (I0 != J0) s += u2[(((d * 9 + J0) * 9 + I0) * PP2) + p];
        su2[(t * PP2 + p) * 9 + d] = s;
    } else if (gid < F3 * PP3 * 9 + F2 * PP2 * 9 + 16) {
        cursors[gid - (F3 * PP3 * 9 + F2 * PP2 * 9)] = 0;
    }
}

// Atomic append bucketing. List ORDER is nondeterministic, but each node's
// result is a fixed-order dot product independent of its list slot, so
// d_out is bit-deterministic.
__global__ void bucket_kernel(const int* __restrict__ indices,
                              int* __restrict__ cursors,
                              int* __restrict__ lists) {
    int b = blockIdx.x * blockDim.x + threadIdx.x;
    if (b < NN) {
        int e = indices[b];
        int slot = atomicAdd(&cursors[e], 1);
        lists[e * NN + slot] = b;
    }
}

// Precompute per-(e,c) f16 weight image, layout [d (9 rows)][f (224, K)].
__global__ __launch_bounds__(256) void wprep16_kernel(
    const float* __restrict__ su3,
    const float* __restrict__ su2,
    const float* __restrict__ u1,
    const float* __restrict__ w3,
    const float* __restrict__ w2,
    const float* __restrict__ w1,
    unsigned* __restrict__ Wg16)
{
    const int c = blockIdx.x;
    const int e = blockIdx.y;
    const int tid = threadIdx.x;

    __shared__ unsigned short sImg[9 * FPAD];   // 4 KB f16 image [d][f]
    unsigned* sImgW = reinterpret_cast<unsigned*>(sImg);
    for (int q = tid; q < 9 * FPAD / 2; q += 256) sImgW[q] = 0u;
    __syncthreads();

    if (tid < FTOT) {
        float acc[9];
        #pragma unroll
        for (int d = 0; d < 9; d++) acc[d] = 0.f;

        if (tid < F3) {
            const float* sp = su3 + (size_t)tid * PP3 * 9;
            #pragma unroll
            for (int p = 0; p < PP3; p++) {
                const float wv = w3[(e * PP3 + p) * CC + c];     // uniform -> SGPR
                const float4 a = *reinterpret_cast<const float4*>(sp + p * 9);
                const float4 b = *reinterpret_cast<const float4*>(sp + p * 9 + 4);
                const float g = sp[p * 9 + 8];
                acc[0] += wv * a.x; acc[1] += wv * a.y; acc[2] += wv * a.z; acc[3] += wv * a.w;
                acc[4] += wv * b.x; acc[5] += wv * b.y; acc[6] += wv * b.z; acc[7] += wv * b.w;
                acc[8] += wv * g;
            }
        } else if (tid < F3 + F2) {
            const float* sp = su2 + (size_t)(tid - F3) * PP2 * 9;
            #pragma unroll
            for (int p = 0; p < PP2; p++) {
                const float wv = w2[(e * PP2 + p) * CC + c];
                const float4 a = *reinterpret_cast<const float4*>(sp + p * 9);
                const float4 b = *reinterpret_cast<const float4*>(sp + p * 9 + 4);
                const float g = sp[p * 9 + 8];
                acc[0] += wv * a.x; acc[1] += wv * a.y; acc[2] += wv * a.z; acc[3] += wv * a.w;
                acc[4] += wv * b.x; acc[5] += wv * b.y; acc[6] += wv * b.z; acc[7] += wv * b.w;
                acc[8] += wv * g;
            }
        } else {
            const int i = tid - F3 - F2;
            #pragma unroll
            for (int p = 0; p < PP1; p++) {
                const float wv = w1[(e * PP1 + p) * CC + c];
                #pragma unroll
                for (int d = 0; d < 9; d++)
                    acc[d] += wv * u1[(d * 9 + i) * PP1 + p];
            }
        }
        #pragma unroll
        for (int d = 0; d < 9; d++)
            sImg[d * FPAD + tid] = h16(acc[d]);
    }
    __syncthreads();

    unsigned* dst = Wg16 + (size_t)(e * CC + c) * (9 * FPAD / 2);
    for (int q = tid; q < 9 * FPAD / 2; q += 256) dst[q] = sImgW[q];
}

// Main kernel, round 14: 32x32x16 MFMA, barrier/LDS-free, channel-blocked,
// two-stage software pipeline. Changes vs r13:
//  - node ids for the scatter come from __shfl of the carried per-lane id
//    (removes 16 uniform L2 loads per tile),
//  - id for tile T+2*TS is prefetched so the lists->x dependent chain never
//    sits on the critical path (each iteration issues only independent loads),
//  - TS=8 (2560 blocks) smooths species imbalance across CUs.
__global__ __launch_bounds__(256, 4) void symcon_reg32_kernel(
    const float* __restrict__ x,
    const unsigned short* __restrict__ Wg16,
    const int* __restrict__ cursors,
    const int* __restrict__ lists,
    float* __restrict__ out)
{
    const int e = blockIdx.y;
    const int lane = threadIdx.x & 63;
    const int wid = threadIdx.x >> 6;
    const int c = blockIdx.x * CPB + wid;
    const int r = lane & 31;       // node row within tile; also B col (= d)
    const int g = lane >> 5;       // k-half
    const bool isg1 = (g == 1);

    // B fragments: lane holds B[k = t*16 + g*8 + j][col = r], zeros for col>=9
    f16x8 bfrag[NKT14];
    {
        const unsigned short* wp = Wg16 + (size_t)(e * CC + c) * (9 * FPAD);
        #pragma unroll
        for (int t = 0; t < NKT14; t++) {
            f16x8 v = {0, 0, 0, 0, 0, 0, 0, 0};
            if (r < 9)
                v = *reinterpret_cast<const f16x8*>(wp + r * FPAD + t * 16 + g * 8);
            bfrag[t] = v;
        }
    }

    const int cnt = cursors[e];
    const int ntiles = (cnt + 31) >> 5;
    const int* lbase = lists + e * NN;
    float* outc = out + (size_t)c * DD;

    int T = blockIdx.z;
    int nb_cur, nb_next;
    float xv[9];
    {
        const int n = T * 32 + r;
        const bool valid = (T < ntiles) && (n < cnt);
        nb_cur = valid ? lbase[n] : 0;
        const float* xr = x + ((size_t)nb_cur * CC + c) * II;
        #pragma unroll
        for (int q = 0; q < 9; q++) xv[q] = valid ? xr[q] : 0.f;
    }
    {
        const int n = (T + TS) * 32 + r;
        const bool valid = (T + TS < ntiles) && (n < cnt);
        nb_next = valid ? lbase[n] : 0;
    }

    while (T < ntiles) {
        // ---- independent prefetches: x row for T+TS (id already in hand),
        //      id for T+2*TS ----
        float xn[9];
        {
            const int n = (T + TS) * 32 + r;
            const bool valid = (T + TS < ntiles) && (n < cnt);
            const float* xr = x + ((size_t)nb_next * CC + c) * II;
            #pragma unroll
            for (int q = 0; q < 9; q++) xn[q] = valid ? xr[q] : 0.f;
        }
        int nb_next2;
        {
            const int n = (T + 2 * TS) * 32 + r;
            const bool valid = (T + 2 * TS < ntiles) && (n < cnt);
            nb_next2 = valid ? lbase[n] : 0;
        }

        // ---- monomial stream with interleaved MFMA ----
        f32x16 acc = {0.f, 0.f, 0.f, 0.f, 0.f, 0.f, 0.f, 0.f,
                      0.f, 0.f, 0.f, 0.f, 0.f, 0.f, 0.f, 0.f};
        unsigned au[4];
        {
            float pend = 0.f;
            int F = 0;
            // Pair P = F>>1: K-tile t = P>>3, q = P&7, dword jd = q&3 — all
            // compile-time after unroll. q<4 writes unconditional (g1 lanes
            // overwritten by their q>=4 select). At q==7 fragment complete
            // -> MFMA.
#define EMITR(expr) { const float _m = (expr);                                \
            if (F & 1) { const unsigned _pk = pkrtz(pend, _m);                \
                const int _P = F >> 1; const int _t = _P >> 3;                \
                const int _q = _P & 7; const int _jd = _q & 3;                \
                if (_q < 4) au[_jd] = _pk;                                    \
                else        au[_jd] = isg1 ? _pk : au[_jd];                   \
                if (_q == 7) {                                                \
                    f16x8 af;                                                 \
                    unsigned* _ap = reinterpret_cast<unsigned*>(&af);         \
                    _ap[0] = au[0]; _ap[1] = au[1];                           \
                    _ap[2] = au[2]; _ap[3] = au[3];                           \
                    acc = __builtin_amdgcn_mfma_f32_32x32x16_f16(             \
                        af, bfrag[_t], acc, 0, 0, 0);                         \
                }                                                             \
            } else pend = _m; F++; }
            #pragma unroll
            for (int i = 0; i < 9; i++)
                #pragma unroll
                for (int j = i; j < 9; j++) {
                    const float xij = xv[i] * xv[j];
                    #pragma unroll
                    for (int k = j; k < 9; k++)
                        EMITR(xij * xv[k])
                }
            #pragma unroll
            for (int i = 0; i < 9; i++)
                #pragma unroll
                for (int j = i; j < 9; j++)
                    EMITR(xv[i] * xv[j])
            #pragma unroll
            for (int i = 0; i < 9; i++)
                EMITR(xv[i])
            #pragma unroll
            for (int z = 0; z < 5; z++)   // zero-pad f 219..223 (exactly 224)
                EMITR(0.f)
#undef EMITR
        }

        // ---- scatter D: col = r (= d), row = (reg&3) + 8*(reg>>2) + 4*g.
        // Node id for row comes from lane 'row' via shfl (all lanes
        // participate; store guarded afterwards). ----
        #pragma unroll
        for (int reg = 0; reg < 16; reg++) {
            const int row = (reg & 3) + 8 * (reg >> 2) + 4 * g;
            const int sb = __shfl(nb_cur, row);
            const int slot = T * 32 + row;
            if (r < 9 && slot < cnt)
                outc[(size_t)sb * (CC * DD) + r] = acc[reg];
        }

        #pragma unroll
        for (int q = 0; q < 9; q++) xv[q] = xn[q];
        nb_cur = nb_next;
        nb_next = nb_next2;
        T += TS;
    }
}

extern "C" void kernel_launch(void* const* d_in, const int* in_sizes, int n_in,
                              void* d_out, int out_size, void* d_ws, size_t ws_size,
                              hipStream_t stream) {
    const float* x   = (const float*)d_in[0];
    const int* indices = (const int*)d_in[1];
    const float* u3  = (const float*)d_in[2];
    const float* u2  = (const float*)d_in[3];
    const float* u1  = (const float*)d_in[4];
    const float* w3  = (const float*)d_in[5];
    const float* w2  = (const float*)d_in[6];
    const float* w1  = (const float*)d_in[7];
    float* out = (float*)d_out;

    char* ws = (char*)d_ws;
    float* su3 = (float*)(ws + SU3_OFF);
    float* su2 = (float*)(ws + SU2_OFF);
    int* cursors = (int*)(ws + CUR_OFF);
    int* lists = (int*)(ws + LIST_OFF);
    unsigned* Wg16 = (unsigned*)(ws + WG16_OFF);

    const int symn = F3 * PP3 * 9 + F2 * PP2 * 9 + 16;
    hipLaunchKernelGGL(sym_u_zero_kernel, dim3((symn + 255) / 256), dim3(256), 0, stream,
                       u3, u2, su3, su2, cursors);
    hipLaunchKernelGGL(bucket_kernel, dim3((NN + 255) / 256), dim3(256), 0, stream,
                       indices, cursors, lists);
    hipLaunchKernelGGL(wprep16_kernel, dim3(CC, EE), dim3(256), 0, stream,
                       su3, su2, u1, w3, w2, w1, Wg16);
    hipLaunchKernelGGL(symcon_reg32_kernel, dim3(CC / CPB, EE, TS), dim3(256), 0, stream,
                       x, (const unsigned short*)Wg16, cursors, lists, out);
}